// Round 1
// baseline (628.581 us; speedup 1.0000x reference)
//
#include <hip/hip_runtime.h>
#include <math.h>

// DepthToVoxelConverter: B=32, C=4 (rgb + depth), H=W=512 -> (B, 4, 64^3)
// out channel 0 = occupancy, channels 1..3 = mean color per voxel.
// Strategy: accumulate count + color sums directly in d_out (atomicAdd),
// then finalize in place.

constexpr int V = 64;
constexpr int V3 = V * V * V;

__global__ void dtv_scatter(const float* __restrict__ rgbd,
                            float* __restrict__ acc,
                            int B, int H, int W) {
    int idx = blockIdx.x * blockDim.x + threadIdx.x;
    int npix = H * W;
    int total = B * npix;
    if (idx >= total) return;
    int b = idx / npix;
    int pix = idx - b * npix;
    int h = pix / W;
    int w = pix - h * W;

    const float* base = rgbd + (size_t)b * 4 * npix;
    float d = base[(size_t)3 * npix + pix];

    // depth_valid = (d > 0) & (d < 10) & isfinite(d)
    if (!(d > 0.0f) || !(d < 10.0f) || !isfinite(d)) return;

    int mhw = (H < W) ? H : W;
    float fx = 0.5f * (float)mhw;        // fy == fx
    float cx = 0.5f * (float)W;
    float cy = 0.5f * (float)H;

    // Match numpy op order/rounding: ((u-cx)*d) rounds once, /fx exact (pow2).
    float x = (((float)w - cx) * d) / fx;
    float y = (((float)h - cy) * d) / fx;

    // (p - SMIN)/(SMAX-SMIN)*(V-1): (p+2) rounds, *0.25 exact, *63 rounds.
    // np.round is half-to-even -> rintf (v_rndne_f32, RNE).
    float tx = rintf(((x + 2.0f) * 0.25f) * 63.0f);
    float ty = rintf(((y + 2.0f) * 0.25f) * 63.0f);
    float tz = rintf(((d + 2.0f) * 0.25f) * 63.0f);
    int ix = (int)tx, iy = (int)ty, iz = (int)tz;
    if (ix < 0 || ix >= V || iy < 0 || iy >= V || iz < 0 || iz >= V) return;

    float r  = base[pix];
    float g  = base[(size_t)npix + pix];
    float bl = base[(size_t)2 * npix + pix];

    float* ob = acc + (size_t)b * 4 * V3;
    int vlin = (ix * V + iy) * V + iz;
    atomicAdd(ob + vlin, 1.0f);                      // count  (channel 0)
    atomicAdd(ob + (size_t)V3 + vlin, r);            // r sum  (channel 1)
    atomicAdd(ob + (size_t)2 * V3 + vlin, g);        // g sum  (channel 2)
    atomicAdd(ob + (size_t)3 * V3 + vlin, bl);       // b sum  (channel 3)
}

__global__ void dtv_finalize(float* __restrict__ out, int B) {
    int idx = blockIdx.x * blockDim.x + threadIdx.x;
    int total = B * V3;
    if (idx >= total) return;
    int b = idx / V3;
    int vlin = idx - b * V3;

    float* p = out + (size_t)b * 4 * V3;
    float c  = p[vlin];
    float r  = p[(size_t)V3 + vlin];
    float g  = p[(size_t)2 * V3 + vlin];
    float bl = p[(size_t)3 * V3 + vlin];

    bool occ = (c > 0.0f);
    float occf = occ ? 1.0f : 0.0f;
    // count >= 1 when occupied, so max(count,1) == count.
    float rr = occ ? (r / c)  : 0.0f;
    float gg = occ ? (g / c)  : 0.0f;
    float bb = occ ? (bl / c) : 0.0f;

    p[vlin]                   = occf;
    p[(size_t)V3 + vlin]      = rr;
    p[(size_t)2 * V3 + vlin]  = gg;
    p[(size_t)3 * V3 + vlin]  = bb;
}

extern "C" void kernel_launch(void* const* d_in, const int* in_sizes, int n_in,
                              void* d_out, int out_size, void* d_ws, size_t ws_size,
                              hipStream_t stream) {
    const float* rgbd = (const float*)d_in[0];
    float* out = (float*)d_out;

    const int H = 512, W = 512;
    const int B = in_sizes[0] / (4 * H * W);   // 32

    // Zero the accumulator (== output) buffer; harness poisons it to 0xAA.
    hipMemsetAsync(d_out, 0, (size_t)out_size * sizeof(float), stream);

    int total_pix = B * H * W;
    dtv_scatter<<<(total_pix + 255) / 256, 256, 0, stream>>>(rgbd, out, B, H, W);

    int total_vox = B * V3;
    dtv_finalize<<<(total_vox + 255) / 256, 256, 0, stream>>>(out, B);
}

// Round 2
// 519.497 us; speedup vs baseline: 1.2100x; 1.2100x over previous
//
#include <hip/hip_runtime.h>
#include <math.h>

// DepthToVoxelConverter: B=32, (B,4,512,512) fp32 -> (B,4,64^3) fp32
// out ch0 = occupancy, ch1..3 = mean rgb per voxel.
//
// R2: scatter was atomic-throughput-bound (19.5G atomics/s, 4 sectors/pixel).
// Pack count+r and g+b into two u64 fixed-point atomics, AoS in d_ws:
// halves atomic ops, and both land in one 32B sector (was 4 sectors, planes
// 1 MiB apart). Colors in Q19.13 (err <= 2^-14 on the mean; thresh 2e-2).
// Overflow-safe: count <= 2^18 per voxel, color sum <= 2^18*2^13 = 2^31 < 2^32.

constexpr int V = 64;
constexpr int V3 = V * V * V;           // 262144 = 2^18
constexpr int Wd = 512, Hd = 512;
constexpr int NPIX = Wd * Hd;           // 262144 = 2^18
constexpr float QSCALE = 8192.0f;       // 2^13

__device__ __forceinline__ bool unproject(int w, int h, float d,
                                          int& ix, int& iy, int& iz) {
    // depth_valid = (d > 0) & (d < 10) & isfinite(d)
    if (!(d > 0.0f) || !(d < 10.0f) || !isfinite(d)) return false;
    const float fx = 256.0f, cx = 256.0f, cy = 256.0f;  // min(H,W)/2, W/2, H/2
    // Match numpy op order: ((u-cx)*d) rounds once, /fx exact (pow2).
    float x = (((float)w - cx) * d) / fx;
    float y = (((float)h - cy) * d) / fx;
    // (p+2) rounds, *0.25 exact, *63 rounds; np.round = RNE -> rintf.
    float tx = rintf(((x + 2.0f) * 0.25f) * 63.0f);
    float ty = rintf(((y + 2.0f) * 0.25f) * 63.0f);
    float tz = rintf(((d + 2.0f) * 0.25f) * 63.0f);
    ix = (int)tx; iy = (int)ty; iz = (int)tz;
    return !(ix < 0 || ix >= V || iy < 0 || iy >= V ||
             iz < 0 || iz >= V);
}

__global__ void dtv_scatter_packed(const float* __restrict__ rgbd,
                                   unsigned long long* __restrict__ acc) {
    int idx = blockIdx.x * blockDim.x + threadIdx.x;   // grid == B*NPIX exactly
    int b   = idx >> 18;
    int pix = idx & (NPIX - 1);
    int h   = pix >> 9;
    int w   = pix & (Wd - 1);

    const float* base = rgbd + (size_t)b * 4 * NPIX;
    float d = base[(size_t)3 * NPIX + pix];

    int ix, iy, iz;
    if (!unproject(w, h, d, ix, iy, iz)) return;

    float r  = base[pix];
    float g  = base[(size_t)NPIX + pix];
    float bl = base[(size_t)2 * NPIX + pix];

    unsigned ri = (unsigned)rintf(r  * QSCALE);
    unsigned gi = (unsigned)rintf(g  * QSCALE);
    unsigned bi = (unsigned)rintf(bl * QSCALE);

    int vlin = (ix * V + iy) * V + iz;
    unsigned long long* p = acc + 2 * ((size_t)b * V3 + vlin);
    atomicAdd(p,     (1ULL << 32) | (unsigned long long)ri);
    atomicAdd(p + 1, ((unsigned long long)gi << 32) | (unsigned long long)bi);
}

__global__ void dtv_finalize_packed(const unsigned long long* __restrict__ acc,
                                    float* __restrict__ out) {
    int idx = blockIdx.x * blockDim.x + threadIdx.x;   // grid == B*V3 exactly
    unsigned long long w1 = acc[(size_t)2 * idx];
    unsigned long long w2 = acc[(size_t)2 * idx + 1];

    unsigned cnt = (unsigned)(w1 >> 32);
    float occ = 0.0f, r = 0.0f, g = 0.0f, bl = 0.0f;
    if (cnt) {
        float inv = 1.0f / (QSCALE * (float)cnt);
        occ = 1.0f;
        r  = (float)(unsigned)(w1 & 0xffffffffu) * inv;
        g  = (float)(unsigned)(w2 >> 32)         * inv;
        bl = (float)(unsigned)(w2 & 0xffffffffu) * inv;
    }

    int b    = idx >> 18;                // V3 == 2^18
    int vlin = idx & (V3 - 1);
    float* p = out + (size_t)b * 4 * V3;
    p[vlin]                  = occ;
    p[(size_t)V3 + vlin]     = r;
    p[(size_t)2 * V3 + vlin] = g;
    p[(size_t)3 * V3 + vlin] = bl;
}

// ---------- fallback (proven R1 path) if ws is too small ----------
__global__ void dtv_scatter_f32(const float* __restrict__ rgbd,
                                float* __restrict__ acc) {
    int idx = blockIdx.x * blockDim.x + threadIdx.x;
    int b   = idx >> 18;
    int pix = idx & (NPIX - 1);
    int h   = pix >> 9;
    int w   = pix & (Wd - 1);

    const float* base = rgbd + (size_t)b * 4 * NPIX;
    float d = base[(size_t)3 * NPIX + pix];
    int ix, iy, iz;
    if (!unproject(w, h, d, ix, iy, iz)) return;

    float r  = base[pix];
    float g  = base[(size_t)NPIX + pix];
    float bl = base[(size_t)2 * NPIX + pix];
    float* ob = acc + (size_t)b * 4 * V3;
    int vlin = (ix * V + iy) * V + iz;
    atomicAdd(ob + vlin, 1.0f);
    atomicAdd(ob + (size_t)V3 + vlin, r);
    atomicAdd(ob + (size_t)2 * V3 + vlin, g);
    atomicAdd(ob + (size_t)3 * V3 + vlin, bl);
}

__global__ void dtv_finalize_f32(float* __restrict__ out) {
    int idx = blockIdx.x * blockDim.x + threadIdx.x;
    int b    = idx >> 18;
    int vlin = idx & (V3 - 1);
    float* p = out + (size_t)b * 4 * V3;
    float c  = p[vlin];
    float r  = p[(size_t)V3 + vlin];
    float g  = p[(size_t)2 * V3 + vlin];
    float bl = p[(size_t)3 * V3 + vlin];
    bool occ = (c > 0.0f);
    p[vlin]                  = occ ? 1.0f : 0.0f;
    p[(size_t)V3 + vlin]     = occ ? (r / c)  : 0.0f;
    p[(size_t)2 * V3 + vlin] = occ ? (g / c)  : 0.0f;
    p[(size_t)3 * V3 + vlin] = occ ? (bl / c) : 0.0f;
}

extern "C" void kernel_launch(void* const* d_in, const int* in_sizes, int n_in,
                              void* d_out, int out_size, void* d_ws, size_t ws_size,
                              hipStream_t stream) {
    const float* rgbd = (const float*)d_in[0];
    float* out = (float*)d_out;
    const int B = in_sizes[0] / (4 * NPIX);   // 32

    size_t acc_bytes = (size_t)B * V3 * 2 * sizeof(unsigned long long);  // 128 MB
    int total_pix = B * NPIX;
    int total_vox = B * V3;

    if (ws_size >= acc_bytes) {
        unsigned long long* acc = (unsigned long long*)d_ws;
        hipMemsetAsync(acc, 0, acc_bytes, stream);
        dtv_scatter_packed<<<total_pix / 256, 256, 0, stream>>>(rgbd, acc);
        dtv_finalize_packed<<<total_vox / 256, 256, 0, stream>>>(acc, out);
    } else {
        hipMemsetAsync(d_out, 0, (size_t)out_size * sizeof(float), stream);
        dtv_scatter_f32<<<total_pix / 256, 256, 0, stream>>>(rgbd, out);
        dtv_finalize_f32<<<total_vox / 256, 256, 0, stream>>>(out);
    }
}